// Round 4
// baseline (253.552 us; speedup 1.0000x reference)
//
#include <hip/hip_runtime.h>
#include <hip/hip_bf16.h>

// Problem constants: N=32, C=3, H=W=512, A=512, SCALE=1, ITERS=5, thr0=4.0f.
#define AN 512
#define NB 32
#define HW 512
#define RSTRIDE 516   // 512 + 4 pad floats (2064 B, 16B-aligned); pad zeroed

__device__ __forceinline__ float waveMax(float v) {
    #pragma unroll
    for (int off = 32; off > 0; off >>= 1) v = fmaxf(v, __shfl_xor(v, off, 64));
    return v;
}
__device__ __forceinline__ float waveSum(float v) {
    #pragma unroll
    for (int off = 32; off > 0; off >>= 1) v += __shfl_xor(v, off, 64);
    return v;
}

// ---------------------------------------------------------------------------
// Kernel 1: water-fill + inverse-CDF coords. ONE WAVE per sample, 8 elements
// per lane held in registers. Zero __syncthreads(): reductions are shfl
// trees, cumsum is per-lane serial scan + shfl_up wave prefix. LDS is used
// only as the random-access table for the binary searches (same-wave LDS
// ops are issue-ordered; no barrier needed).
// ---------------------------------------------------------------------------
__global__ __launch_bounds__(64) void waterfill_coords_kernel(
    const float* __restrict__ attx, const float* __restrict__ atty,
    float* __restrict__ gx, float* __restrict__ gy)
{
    __shared__ float axs[AN], ays[AN], csx[AN], csy[AN];
    const int n = blockIdx.x;
    const int lane = threadIdx.x;      // 0..63
    const int b = lane << 3;           // this lane owns elements [b, b+8)

    float ax[8], ay[8];
    {
        const float4 x0 = ((const float4*)(attx + n * AN + b))[0];
        const float4 x1 = ((const float4*)(attx + n * AN + b))[1];
        const float4 y0 = ((const float4*)(atty + n * AN + b))[0];
        const float4 y1 = ((const float4*)(atty + n * AN + b))[1];
        ax[0] = x0.x * 512.0f; ax[1] = x0.y * 512.0f; ax[2] = x0.z * 512.0f; ax[3] = x0.w * 512.0f;
        ax[4] = x1.x * 512.0f; ax[5] = x1.y * 512.0f; ax[6] = x1.z * 512.0f; ax[7] = x1.w * 512.0f;
        ay[0] = y0.x * 512.0f; ay[1] = y0.y * 512.0f; ay[2] = y0.z * 512.0f; ay[3] = y0.w * 512.0f;
        ay[4] = y1.x * 512.0f; ay[5] = y1.y * 512.0f; ay[6] = y1.z * 512.0f; ay[7] = y1.w * 512.0f;
    }

    #pragma unroll
    for (int j = 0; j < 5; ++j) {
        float mx = ax[0], my = ay[0];
        #pragma unroll
        for (int i = 1; i < 8; ++i) { mx = fmaxf(mx, ax[i]); my = fmaxf(my, ay[i]); }
        mx = waveMax(mx); my = waveMax(my);
        float thr = fminf(mx, my);
        if (j == 0) thr = fminf(thr, 4.0f);
        float sx = 0.0f, sy = 0.0f;
        #pragma unroll
        for (int i = 0; i < 8; ++i) {
            ax[i] = fminf(ax[i], thr); ay[i] = fminf(ay[i], thr);
            sx += ax[i]; sy += ay[i];
        }
        sx = waveSum(sx); sy = waveSum(sy);
        const float dx = (512.0f - sx) * (1.0f / 512.0f);
        const float dy = (512.0f - sy) * (1.0f / 512.0f);
        #pragma unroll
        for (int i = 0; i < 8; ++i) { ax[i] += dx; ay[i] += dy; }
    }

    if (lane == 0) { ax[0] = 1.0f; ay[0] = 1.0f; }

    // inclusive scan: serial per-lane over 8, shfl_up wave prefix of totals
    float cxl[8], cyl[8];
    float rx = 0.0f, ry = 0.0f;
    #pragma unroll
    for (int i = 0; i < 8; ++i) { rx += ax[i]; cxl[i] = rx; ry += ay[i]; cyl[i] = ry; }
    float tx = rx, ty = ry;
    #pragma unroll
    for (int off = 1; off < 64; off <<= 1) {
        const float ux = __shfl_up(tx, off, 64);
        const float uy = __shfl_up(ty, off, 64);
        if (lane >= off) { tx += ux; ty += uy; }
    }
    const float ex = tx - rx, ey = ty - ry;   // exclusive wave prefix
    #pragma unroll
    for (int i = 0; i < 8; ++i) { cxl[i] += ex; cyl[i] += ey; }

    // totals come from lane 63's inclusive prefix (no LDS round-trip)
    const float lastx = __shfl(tx, 63, 64);
    const float lasty = __shfl(ty, 63, 64);

    // publish search tables to LDS (same-wave: no barrier required)
    #pragma unroll
    for (int i = 0; i < 8; ++i) {
        axs[b + i] = ax[i]; ays[b + i] = ay[i];
        csx[b + i] = cxl[i]; csy[b + i] = cyl[i];
    }

    const float stepx = lastx * (1.0f / 512.0f);
    const float stepy = lasty * (1.0f / 512.0f);
    float oy[8], ox[8];
    #pragma unroll
    for (int i = 0; i < 8; ++i) {
        const int t = b + i;
        const float tvx = (float)(t + 1) * stepx;
        const float tvy = (float)(t + 1) * stepy;
        int lox = 0, hix = AN, loy = 0, hiy = AN;
        #pragma unroll
        for (int s = 0; s < 9; ++s) {
            const int mx_ = (lox + hix) >> 1;
            const int my_ = (loy + hiy) >> 1;
            if (csx[mx_] < tvx) lox = mx_ + 1; else hix = mx_;
            if (csy[my_] < tvy) loy = my_ + 1; else hiy = my_;
        }
        // exact 10th probe: interval size is now 0 or 1 (513-answer space)
        if (lox < hix && csx[lox] < tvx) ++lox;
        if (loy < hiy && csy[loy] < tvy) ++loy;
        const int jx = lox > (AN - 1) ? (AN - 1) : lox;
        const int jy = loy > (AN - 1) ? (AN - 1) : loy;
        const float prevx = (jx > 0) ? csx[jx - 1] : 0.0f;
        const float prevy = (jy > 0) ? csy[jy - 1] : 0.0f;
        oy[i] = ((float)jx + (tvx - prevx) / fmaxf(axs[jx], 1e-12f)) * (2.0f / 512.0f) - 1.0f;
        ox[i] = ((float)jy + (tvy - prevy) / fmaxf(ays[jy], 1e-12f)) * (2.0f / 512.0f) - 1.0f;
    }
    // contiguous 8-float stores per lane -> compiler merges to dwordx4 pairs
    #pragma unroll
    for (int i = 0; i < 8; ++i) {
        gy[n * AN + b + i] = oy[i];
        gx[n * AN + b + i] = ox[i];
    }
}

// ---------------------------------------------------------------------------
// Kernel 2: separable bilinear grid-sample via LDS row staging.
// One block per (ho, n), XCD-bijective swizzle (each XCD gets 4 contiguous
// samples -> row re-reads are L2 hits). Staging via global_load_lds w=16.
// Gather reads rows[c][xb] and rows[c][xb+1] from the same base -> compiler
// merges to ds_read2_b32 (halves LDS gather instructions). Row stride 516
// with zeroed pad makes xb+1==512 read 0.0; the lo_ok select fixes the
// x0f==-1 index shift (weights vx0/vx1 zero the OOB terms as before).
// ---------------------------------------------------------------------------
__global__ __launch_bounds__(256) void grid_sample_kernel(
    const float* __restrict__ data, const float* __restrict__ gx,
    const float* __restrict__ gy, float* __restrict__ outS,
    float* __restrict__ outG)
{
    __shared__ __align__(16) float rows[6][RSTRIDE];  // [y0:c0,c1,c2 | y1:c0,c1,c2]
    const int t   = threadIdx.x;
    const int lid = blockIdx.x;
    // bijective XCD swizzle: 16384 blocks, 8 XCDs, 2048 contiguous wg per XCD
    const int wg  = (lid & 7) * 2048 + (lid >> 3);
    const int n   = wg >> 9;
    const int ho  = wg & 511;
    const int wid = t >> 6;
    const int lane = t & 63;

    const float gyv = gy[n * AN + ho];
    const float y   = (gyv + 1.0f) * 256.0f - 0.5f;
    const float y0f = floorf(y);
    const float wy1 = y - y0f, wy0 = 1.0f - wy1;
    const float vy0 = ((y0f >= 0.0f) & (y0f < 512.0f)) ? 1.0f : 0.0f;
    const float vy1 = ((y0f >= -1.0f) & (y0f < 511.0f)) ? 1.0f : 0.0f;
    const int y0 = (int)fminf(fmaxf(y0f, 0.0f), 511.0f);
    const int y1 = (int)fminf(fmaxf(y0f + 1.0f, 0.0f), 511.0f);

    // stage 6 source rows (2 y x 3 c) = 768 float4, 3 per thread, async to LDS
    const float* base = data + (size_t)n * 3 * HW * HW;
    #pragma unroll
    for (int r = 0; r < 3; ++r) {
        const int idx0 = r * 256 + (wid << 6);   // wave-uniform
        const int row0 = idx0 >> 7;              // 0..5, wave-uniform
        const int col0 = idx0 & 127;             // float4 index 0 or 64, wave-uniform
        const int yy   = (row0 < 3) ? y0 : y1;
        const int c    = (row0 < 3) ? row0 : row0 - 3;
        const float* g = base + ((size_t)c * HW + yy) * HW + ((col0 + lane) << 2);
        __builtin_amdgcn_global_load_lds(
            (const __attribute__((address_space(1))) void*)g,
            (__attribute__((address_space(3))) void*)(&rows[row0][col0 << 2]),
            16, 0, 0);
    }
    if (t < 24) rows[t >> 2][512 + (t & 3)] = 0.0f;   // zero the pads
    __syncthreads();   // drains vmcnt+lgkm -> staging and pad-zero complete

    // 2 consecutive px per thread
    const float2 gx2 = ((const float2*)(gx + n * AN))[t];
    const float xg[2] = {gx2.x, gx2.y};
    float res[3][2];

    #pragma unroll
    for (int k = 0; k < 2; ++k) {
        const float gxv = xg[k];
        const float x   = (gxv + 1.0f) * 256.0f - 0.5f;
        const float x0f = floorf(x);
        const float wx1 = x - x0f, wx0 = 1.0f - wx1;
        const float vx0 = ((x0f >= 0.0f) & (x0f < 512.0f)) ? 1.0f : 0.0f;
        const float vx1 = ((x0f >= -1.0f) & (x0f < 511.0f)) ? 1.0f : 0.0f;
        const int xb = (int)fminf(fmaxf(x0f, 0.0f), 511.0f);
        const bool lo_ok = (x0f >= 0.0f);
        const float w00 = wx0 * wy0 * vx0 * vy0;
        const float w10 = wx1 * wy0 * vx1 * vy0;
        const float w01 = wx0 * wy1 * vx0 * vy1;
        const float w11 = wx1 * wy1 * vx1 * vy1;
        #pragma unroll
        for (int c = 0; c < 3; ++c) {
            const float a0 = rows[c][xb],     a1 = rows[c][xb + 1];      // ds_read2
            const float b0 = rows[3 + c][xb], b1 = rows[3 + c][xb + 1];  // ds_read2
            const float v10 = lo_ok ? a1 : a0;   // x0f==-1: x1 value lives at xb
            const float v11 = lo_ok ? b1 : b0;
            res[c][k] = a0 * w00 + v10 * w10 + b0 * w01 + v11 * w11;
        }
    }

    const int wo = 2 * t;
    const size_t o = (((size_t)n * 3) * HW + ho) * HW + wo;
    #pragma unroll
    for (int c = 0; c < 3; ++c)
        *(float2*)(outS + o + (size_t)c * HW * HW) = make_float2(res[c][0], res[c][1]);

    *(float4*)(outG + (((size_t)n * HW + ho) * HW + wo) * 2) =
        make_float4(gx2.x, gyv, gx2.y, gyv);
}

extern "C" void kernel_launch(void* const* d_in, const int* in_sizes, int n_in,
                              void* d_out, int out_size, void* d_ws, size_t ws_size,
                              hipStream_t stream) {
    const float* data = (const float*)d_in[0];   // (32,3,512,512)
    const float* attx = (const float*)d_in[1];   // (32,512)
    const float* atty = (const float*)d_in[2];   // (32,512)

    float* gx = (float*)d_ws;            // (32,512) width coords
    float* gy = gx + NB * AN;            // (32,512) height coords

    float* outS = (float*)d_out;                          // sampled (32,3,512,512)
    float* outG = outS + (size_t)NB * 3 * HW * HW;        // grid (32,512,512,2)

    waterfill_coords_kernel<<<NB, 64, 0, stream>>>(attx, atty, gx, gy);

    grid_sample_kernel<<<NB * HW, 256, 0, stream>>>(data, gx, gy, outS, outG);
}